// Round 2
// baseline (4347.596 us; speedup 1.0000x reference)
//
#include <hip/hip_runtime.h>

#define NN   100000
#define EE   3200000
#define KDIM 1433
#define HID  16
#define H2P  8
#define OUTD 7

// ---- gemm1 tiling ----
#define KC    128
#define RB    64
#define XSTR  133            // odd -> lane stride 5 mod 32 -> 2-way LDS aliasing = free
#define NCHUNK ((KDIM + KC - 1) / KC)   // 12

__global__ void k_init_deg(float* __restrict__ deg) {
    int i = blockIdx.x * blockDim.x + threadIdx.x;
    if (i < NN) deg[i] = 1.0f;           // self-loop contributes 1
}

__global__ void k_deg(const int* __restrict__ ei, float* __restrict__ deg) {
    int e = blockIdx.x * blockDim.x + threadIdx.x;
    if (e < EE) atomicAdd(&deg[ei[e]], 1.0f);   // row = ei[0][e]
}

__global__ void k_dinv(float* __restrict__ deg) {
    int i = blockIdx.x * blockDim.x + threadIdx.x;
    if (i < NN) deg[i] = rsqrtf(deg[i]);        // deg >= 1 always
}

// h1[N][16] = x[N][1433] @ W1[1433][16];  agg1 initialized with self-loop term
__global__ __launch_bounds__(256) void k_gemm1(const float* __restrict__ x,
                                               const float* __restrict__ W1,
                                               const float* __restrict__ dinv,
                                               float* __restrict__ h1,
                                               float* __restrict__ agg1) {
    __shared__ __align__(16) float xs[RB * XSTR];   // 34 KB -> 4 blocks/CU
    const int tid = threadIdx.x;
    // readfirstlane forces the wave index uniform -> W1 loads become s_load (SMEM)
    const int wu  = __builtin_amdgcn_readfirstlane(tid >> 6);
    const int L   = tid & 63;     // lane = local row
    const int r0  = blockIdx.x * RB;

    float acc[HID];
#pragma unroll
    for (int j = 0; j < HID; ++j) acc[j] = 0.f;

    for (int c = 0; c < NCHUNK; ++c) {
        const int c0 = c * KC;
        const int kvalid = (KDIM - c0 < KC) ? (KDIM - c0) : KC;
        __syncthreads();
        // stage 64 rows x 128 k, coalesced dword loads (rows are odd-length -> no f4 alignment)
#pragma unroll
        for (int m = 0; m < (RB * KC) / 256; ++m) {   // 32
            int idx = m * 256 + tid;
            int rr  = idx >> 7;          // / KC
            int kk  = idx & (KC - 1);
            int gr  = r0 + rr;
            float v = 0.f;
            if (gr < NN && kk < kvalid) v = x[(size_t)gr * KDIM + c0 + kk];
            xs[rr * XSTR + kk] = v;
        }
        __syncthreads();
        // wave wu covers kk in [wu*32, wu*32+32); W1 address fully uniform -> s_load
        int kend = kvalid - wu * 32;
        kend = kend < 0 ? 0 : (kend > 32 ? 32 : kend);
        const float* wbase = W1 + (size_t)(c0 + wu * 32) * HID;
        const float* xbase = xs + L * XSTR + wu * 32;
#pragma unroll 4
        for (int i = 0; i < kend; ++i) {
            float xv = xbase[i];
            const float* wr = wbase + i * HID;
#pragma unroll
            for (int j = 0; j < HID; ++j) acc[j] = fmaf(xv, wr[j], acc[j]);
        }
    }
    __syncthreads();
    // cross-wave k-reduction via LDS (alias xs; 16 KB needed <= 34 KB)
    float4* red4 = reinterpret_cast<float4*>(xs);
    red4[(wu * 64 + L) * 4 + 0] = make_float4(acc[0], acc[1], acc[2], acc[3]);
    red4[(wu * 64 + L) * 4 + 1] = make_float4(acc[4], acc[5], acc[6], acc[7]);
    red4[(wu * 64 + L) * 4 + 2] = make_float4(acc[8], acc[9], acc[10], acc[11]);
    red4[(wu * 64 + L) * 4 + 3] = make_float4(acc[12], acc[13], acc[14], acc[15]);
    __syncthreads();
    int rr = tid >> 2, jj = tid & 3;
    float4 a = red4[(0 * 64 + rr) * 4 + jj];
    float4 b = red4[(1 * 64 + rr) * 4 + jj];
    float4 cfr = red4[(2 * 64 + rr) * 4 + jj];
    float4 d = red4[(3 * 64 + rr) * 4 + jj];
    float4 s = make_float4(a.x + b.x + cfr.x + d.x, a.y + b.y + cfr.y + d.y,
                           a.z + b.z + cfr.z + d.z, a.w + b.w + cfr.w + d.w);
    int gr = r0 + rr;
    if (gr < NN) {
        float di = dinv[gr];
        float d2 = di * di;
        reinterpret_cast<float4*>(h1)[(size_t)gr * 4 + jj] = s;
        // fused self-loop init: agg1 = h1 * dinv^2
        reinterpret_cast<float4*>(agg1)[(size_t)gr * 4 + jj] =
            make_float4(s.x * d2, s.y * d2, s.z * d2, s.w * d2);
    }
}

// one thread per edge: agg1[r][0..15] += h1[c][0..15] * dinv[r]*dinv[c]
__global__ void k_scatter1(const int* __restrict__ ei, const float* __restrict__ dinv,
                           const float* __restrict__ h1, float* __restrict__ agg1) {
    int e = blockIdx.x * blockDim.x + threadIdx.x;
    if (e >= EE) return;
    int r = ei[e], c = ei[EE + e];
    float nrm = dinv[r] * dinv[c];
    const float4* hp = reinterpret_cast<const float4*>(h1 + (size_t)c * HID);
    float4 a = hp[0], b = hp[1], cc = hp[2], d = hp[3];
    float* dst = agg1 + (size_t)r * HID;
    atomicAdd(dst + 0,  a.x * nrm);  atomicAdd(dst + 1,  a.y * nrm);
    atomicAdd(dst + 2,  a.z * nrm);  atomicAdd(dst + 3,  a.w * nrm);
    atomicAdd(dst + 4,  b.x * nrm);  atomicAdd(dst + 5,  b.y * nrm);
    atomicAdd(dst + 6,  b.z * nrm);  atomicAdd(dst + 7,  b.w * nrm);
    atomicAdd(dst + 8,  cc.x * nrm); atomicAdd(dst + 9,  cc.y * nrm);
    atomicAdd(dst + 10, cc.z * nrm); atomicAdd(dst + 11, cc.w * nrm);
    atomicAdd(dst + 12, d.x * nrm);  atomicAdd(dst + 13, d.y * nrm);
    atomicAdd(dst + 14, d.z * nrm);  atomicAdd(dst + 15, d.w * nrm);
}

// h2p[i][0..8) = relu(agg1[i]+b1) @ W2 (padded to 8); agg2p initialized with self-loop
__global__ void k_mlp2(const float* __restrict__ agg1, const float* __restrict__ b1,
                       const float* __restrict__ W2, const float* __restrict__ dinv,
                       float* __restrict__ h2p, float* __restrict__ agg2p) {
    int i = blockIdx.x * blockDim.x + threadIdx.x;
    if (i >= NN) return;
    const float4* a4 = reinterpret_cast<const float4*>(agg1 + (size_t)i * HID);
    float4 t0 = a4[0], t1 = a4[1], t2 = a4[2], t3 = a4[3];
    float v[16] = {t0.x, t0.y, t0.z, t0.w, t1.x, t1.y, t1.z, t1.w,
                   t2.x, t2.y, t2.z, t2.w, t3.x, t3.y, t3.z, t3.w};
#pragma unroll
    for (int k = 0; k < 16; ++k) v[k] = fmaxf(v[k] + b1[k], 0.f);
    float o[8] = {0.f, 0.f, 0.f, 0.f, 0.f, 0.f, 0.f, 0.f};
#pragma unroll
    for (int k = 0; k < 16; ++k)
#pragma unroll
        for (int j = 0; j < 7; ++j) o[j] = fmaf(v[k], W2[k * 7 + j], o[j]);
    float di = dinv[i];
    float d2 = di * di;
    float4* hp = reinterpret_cast<float4*>(h2p + (size_t)i * H2P);
    float4* ap = reinterpret_cast<float4*>(agg2p + (size_t)i * H2P);
    hp[0] = make_float4(o[0], o[1], o[2], o[3]);
    hp[1] = make_float4(o[4], o[5], o[6], 0.f);
    ap[0] = make_float4(o[0] * d2, o[1] * d2, o[2] * d2, o[3] * d2);
    ap[1] = make_float4(o[4] * d2, o[5] * d2, o[6] * d2, 0.f);
}

// one thread per edge: agg2p[r][0..7) += h2p[c][0..7) * nrm
__global__ void k_scatter2(const int* __restrict__ ei, const float* __restrict__ dinv,
                           const float* __restrict__ h2p, float* __restrict__ agg2p) {
    int e = blockIdx.x * blockDim.x + threadIdx.x;
    if (e >= EE) return;
    int r = ei[e], c = ei[EE + e];
    float nrm = dinv[r] * dinv[c];
    const float4* hp = reinterpret_cast<const float4*>(h2p + (size_t)c * H2P);
    float4 a = hp[0], b = hp[1];
    float* dst = agg2p + (size_t)r * H2P;
    atomicAdd(dst + 0, a.x * nrm); atomicAdd(dst + 1, a.y * nrm);
    atomicAdd(dst + 2, a.z * nrm); atomicAdd(dst + 3, a.w * nrm);
    atomicAdd(dst + 4, b.x * nrm); atomicAdd(dst + 5, b.y * nrm);
    atomicAdd(dst + 6, b.z * nrm);
}

__global__ void k_logsoftmax(const float* __restrict__ agg2p, const float* __restrict__ b2,
                             float* __restrict__ out) {
    int i = blockIdx.x * blockDim.x + threadIdx.x;
    if (i >= NN) return;
    const float4* ap = reinterpret_cast<const float4*>(agg2p + (size_t)i * H2P);
    float4 a = ap[0], b = ap[1];
    float v[7] = {a.x, a.y, a.z, a.w, b.x, b.y, b.z};
#pragma unroll
    for (int j = 0; j < 7; ++j) v[j] += b2[j];
    float m = v[0];
#pragma unroll
    for (int j = 1; j < 7; ++j) m = fmaxf(m, v[j]);
    float ssum = 0.f;
#pragma unroll
    for (int j = 0; j < 7; ++j) ssum += expf(v[j] - m);
    float ls = logf(ssum);
#pragma unroll
    for (int j = 0; j < 7; ++j) out[(size_t)i * OUTD + j] = v[j] - m - ls;
}

extern "C" void kernel_launch(void* const* d_in, const int* in_sizes, int n_in,
                              void* d_out, int out_size, void* d_ws, size_t ws_size,
                              hipStream_t stream) {
    const float* x  = (const float*)d_in[0];
    const int*   ei = (const int*)d_in[1];     // [2, E] flattened, int32
    const float* W1 = (const float*)d_in[2];
    const float* b1 = (const float*)d_in[3];
    const float* W2 = (const float*)d_in[4];
    const float* b2 = (const float*)d_in[5];
    float* out = (float*)d_out;
    float* ws  = (float*)d_ws;

    float* dinv  = ws;                       // N
    float* h1    = ws + NN;                  // 16N
    float* agg1  = ws + NN + 16 * NN;        // 16N   (peak ws: 33N floats = 13.2 MB)
    float* h2p   = h1;                       // 8N, reuses dead h1
    float* agg2p = h1 + 8 * NN;              // 8N

    hipLaunchKernelGGL(k_init_deg, dim3((NN + 255) / 256), dim3(256), 0, stream, dinv);
    hipLaunchKernelGGL(k_deg, dim3((EE + 255) / 256), dim3(256), 0, stream, ei, dinv);
    hipLaunchKernelGGL(k_dinv, dim3((NN + 255) / 256), dim3(256), 0, stream, dinv);
    hipLaunchKernelGGL(k_gemm1, dim3((NN + RB - 1) / RB), dim3(256), 0, stream,
                       x, W1, dinv, h1, agg1);
    hipLaunchKernelGGL(k_scatter1, dim3((EE + 255) / 256), dim3(256), 0, stream,
                       ei, dinv, h1, agg1);
    hipLaunchKernelGGL(k_mlp2, dim3((NN + 255) / 256), dim3(256), 0, stream,
                       agg1, b1, W2, dinv, h2p, agg2p);
    hipLaunchKernelGGL(k_scatter2, dim3((EE + 255) / 256), dim3(256), 0, stream,
                       ei, dinv, h2p, agg2p);
    hipLaunchKernelGGL(k_logsoftmax, dim3((NN + 255) / 256), dim3(256), 0, stream,
                       agg2p, b2, out);
}

// Round 3
// 864.758 us; speedup vs baseline: 5.0275x; 5.0275x over previous
//
#include <hip/hip_runtime.h>

#define NN   100000
#define EE   3200000
#define KDIM 1433
#define HID  16
#define H2P  8
#define OUTD 7

// ---- gemm1 tiling ----
#define KC    128
#define RB    64
#define XSTR  133            // odd -> lane stride 5 mod 32 -> 2-way LDS aliasing = free
#define NCHUNK ((KDIM + KC - 1) / KC)   // 12

// ============================ degree / norm ============================

__global__ void k_zero_i32(int* __restrict__ p, int n) {
    int i = blockIdx.x * blockDim.x + threadIdx.x;
    if (i < n) p[i] = 0;
}

__global__ void k_count(const int* __restrict__ ei, int* __restrict__ cnt) {
    int e = blockIdx.x * blockDim.x + threadIdx.x;
    if (e < EE) atomicAdd(&cnt[ei[e]], 1);      // row = ei[0][e]
}

__global__ void k_dinv_from_cnt(const int* __restrict__ cnt, float* __restrict__ dinv) {
    int i = blockIdx.x * blockDim.x + threadIdx.x;
    if (i < NN) dinv[i] = rsqrtf((float)cnt[i] + 1.0f);   // +1 self-loop
}

// single-block exclusive scan of cnt[NN] -> rowptr[NN+1], cursor[NN]
__global__ __launch_bounds__(1024) void k_scan(const int* __restrict__ cnt,
                                               int* __restrict__ rowptr,
                                               int* __restrict__ cursor) {
    __shared__ int spart[16];
    __shared__ int soff_s;
    const int tid = threadIdx.x;
    const int L = tid & 63;
    const int w = tid >> 6;
    if (tid == 0) soff_s = 0;
    __syncthreads();
    for (int base = 0; base < NN; base += 4096) {
        int i0 = base + tid * 4;
        int v0 = (i0 + 0 < NN) ? cnt[i0 + 0] : 0;
        int v1 = (i0 + 1 < NN) ? cnt[i0 + 1] : 0;
        int v2 = (i0 + 2 < NN) ? cnt[i0 + 2] : 0;
        int v3 = (i0 + 3 < NN) ? cnt[i0 + 3] : 0;
        int local = v0 + v1 + v2 + v3;
        // wave-level inclusive scan (no barriers)
        int s = local;
#pragma unroll
        for (int ofs = 1; ofs < 64; ofs <<= 1) {
            int n = __shfl_up(s, ofs, 64);
            if (L >= ofs) s += n;
        }
        if (L == 63) spart[w] = s;
        __syncthreads();
        if (w == 0) {
            int p = (L < 16) ? spart[L] : 0;
#pragma unroll
            for (int ofs = 1; ofs < 16; ofs <<= 1) {
                int n = __shfl_up(p, ofs, 64);
                if (L >= ofs) p += n;
            }
            if (L < 16) spart[L] = p;
        }
        __syncthreads();
        int waveoff = (w > 0) ? spart[w - 1] : 0;
        int excl = soff_s + waveoff + s - local;
        if (i0 + 0 < NN) { rowptr[i0 + 0] = excl; cursor[i0 + 0] = excl; excl += v0; }
        if (i0 + 1 < NN) { rowptr[i0 + 1] = excl; cursor[i0 + 1] = excl; excl += v1; }
        if (i0 + 2 < NN) { rowptr[i0 + 2] = excl; cursor[i0 + 2] = excl; excl += v2; }
        if (i0 + 3 < NN) { rowptr[i0 + 3] = excl; cursor[i0 + 3] = excl; excl += v3; }
        __syncthreads();
        if (tid == 0) soff_s += spart[15];
        __syncthreads();
    }
    if (tid == 0) rowptr[NN] = soff_s;
}

__global__ void k_place(const int* __restrict__ ei, int* __restrict__ cursor,
                        int* __restrict__ scol) {
    int e = blockIdx.x * blockDim.x + threadIdx.x;
    if (e >= EE) return;
    int r = ei[e], c = ei[EE + e];
    int p = atomicAdd(&cursor[r], 1);
    scol[p] = c;
}

// ============================ layer 1 GEMM ============================

// h1[N][16] = x[N][1433] @ W1[1433][16]
__global__ __launch_bounds__(256) void k_gemm1(const float* __restrict__ x,
                                               const float* __restrict__ W1,
                                               float* __restrict__ h1) {
    __shared__ __align__(16) float xs[RB * XSTR];   // 34 KB -> 4 blocks/CU
    const int tid = threadIdx.x;
    // readfirstlane forces the wave index uniform -> W1 loads become s_load (SMEM)
    const int wu  = __builtin_amdgcn_readfirstlane(tid >> 6);
    const int L   = tid & 63;     // lane = local row
    const int r0  = blockIdx.x * RB;

    float acc[HID];
#pragma unroll
    for (int j = 0; j < HID; ++j) acc[j] = 0.f;

    for (int c = 0; c < NCHUNK; ++c) {
        const int c0 = c * KC;
        const int kvalid = (KDIM - c0 < KC) ? (KDIM - c0) : KC;
        __syncthreads();
#pragma unroll
        for (int m = 0; m < (RB * KC) / 256; ++m) {   // 32
            int idx = m * 256 + tid;
            int rr  = idx >> 7;          // / KC
            int kk  = idx & (KC - 1);
            int gr  = r0 + rr;
            float v = 0.f;
            if (gr < NN && kk < kvalid) v = x[(size_t)gr * KDIM + c0 + kk];
            xs[rr * XSTR + kk] = v;
        }
        __syncthreads();
        int kend = kvalid - wu * 32;
        kend = kend < 0 ? 0 : (kend > 32 ? 32 : kend);
        const float* wbase = W1 + (size_t)(c0 + wu * 32) * HID;
        const float* xbase = xs + L * XSTR + wu * 32;
#pragma unroll 4
        for (int i = 0; i < kend; ++i) {
            float xv = xbase[i];
            const float* wr = wbase + i * HID;
#pragma unroll
            for (int j = 0; j < HID; ++j) acc[j] = fmaf(xv, wr[j], acc[j]);
        }
    }
    __syncthreads();
    float4* red4 = reinterpret_cast<float4*>(xs);
    red4[(wu * 64 + L) * 4 + 0] = make_float4(acc[0], acc[1], acc[2], acc[3]);
    red4[(wu * 64 + L) * 4 + 1] = make_float4(acc[4], acc[5], acc[6], acc[7]);
    red4[(wu * 64 + L) * 4 + 2] = make_float4(acc[8], acc[9], acc[10], acc[11]);
    red4[(wu * 64 + L) * 4 + 3] = make_float4(acc[12], acc[13], acc[14], acc[15]);
    __syncthreads();
    int rr = tid >> 2, jj = tid & 3;
    float4 a = red4[(0 * 64 + rr) * 4 + jj];
    float4 b = red4[(1 * 64 + rr) * 4 + jj];
    float4 cfr = red4[(2 * 64 + rr) * 4 + jj];
    float4 d = red4[(3 * 64 + rr) * 4 + jj];
    float4 s = make_float4(a.x + b.x + cfr.x + d.x, a.y + b.y + cfr.y + d.y,
                           a.z + b.z + cfr.z + d.z, a.w + b.w + cfr.w + d.w);
    int gr = r0 + rr;
    if (gr < NN) reinterpret_cast<float4*>(h1)[(size_t)gr * 4 + jj] = s;
}

// ============================ CSR gather aggregation ============================

// 4 rows/block (1 wave each). lane = 16 edge-slots x 4 float4-quarters.
__global__ __launch_bounds__(256) void k_agg1(const int* __restrict__ rowptr,
                                              const int* __restrict__ scol,
                                              const float* __restrict__ dinv,
                                              const float* __restrict__ h1,
                                              float* __restrict__ agg1) {
    int row = blockIdx.x * 4 + (threadIdx.x >> 6);
    int L = threadIdx.x & 63;
    int ee = L >> 2;        // 0..15 edge slot
    int q  = L & 3;         // float4 quarter of the 16-float row
    int s = rowptr[row], eend = rowptr[row + 1];
    float dr = dinv[row];
    const float4* h4 = reinterpret_cast<const float4*>(h1);
    float4 acc = make_float4(0.f, 0.f, 0.f, 0.f);
    for (int k = s + ee; k < eend; k += 16) {
        int c = scol[k];
        float dc = dinv[c];
        float4 hv = h4[(size_t)c * 4 + q];
        acc.x = fmaf(hv.x, dc, acc.x);
        acc.y = fmaf(hv.y, dc, acc.y);
        acc.z = fmaf(hv.z, dc, acc.z);
        acc.w = fmaf(hv.w, dc, acc.w);
    }
#pragma unroll
    for (int mask = 4; mask <= 32; mask <<= 1) {
        acc.x += __shfl_xor(acc.x, mask, 64);
        acc.y += __shfl_xor(acc.y, mask, 64);
        acc.z += __shfl_xor(acc.z, mask, 64);
        acc.w += __shfl_xor(acc.w, mask, 64);
    }
    float4 sv = h4[(size_t)row * 4 + q];
    acc.x = (acc.x + sv.x * dr) * dr;
    acc.y = (acc.y + sv.y * dr) * dr;
    acc.z = (acc.z + sv.z * dr) * dr;
    acc.w = (acc.w + sv.w * dr) * dr;
    if (L < 4) reinterpret_cast<float4*>(agg1)[(size_t)row * 4 + q] = acc;
}

// h2p[i][0..8) = relu(agg1[i]+b1) @ W2 (padded); if agg2p != null also write selfloop init
__global__ void k_mlp2(const float* __restrict__ agg1, const float* __restrict__ b1,
                       const float* __restrict__ W2, const float* __restrict__ dinv,
                       float* __restrict__ h2p, float* __restrict__ agg2p) {
    int i = blockIdx.x * blockDim.x + threadIdx.x;
    if (i >= NN) return;
    const float4* a4 = reinterpret_cast<const float4*>(agg1 + (size_t)i * HID);
    float4 t0 = a4[0], t1 = a4[1], t2 = a4[2], t3 = a4[3];
    float v[16] = {t0.x, t0.y, t0.z, t0.w, t1.x, t1.y, t1.z, t1.w,
                   t2.x, t2.y, t2.z, t2.w, t3.x, t3.y, t3.z, t3.w};
#pragma unroll
    for (int k = 0; k < 16; ++k) v[k] = fmaxf(v[k] + b1[k], 0.f);
    float o[8] = {0.f, 0.f, 0.f, 0.f, 0.f, 0.f, 0.f, 0.f};
#pragma unroll
    for (int k = 0; k < 16; ++k)
#pragma unroll
        for (int j = 0; j < 7; ++j) o[j] = fmaf(v[k], W2[k * 7 + j], o[j]);
    float4* hp = reinterpret_cast<float4*>(h2p + (size_t)i * H2P);
    hp[0] = make_float4(o[0], o[1], o[2], o[3]);
    hp[1] = make_float4(o[4], o[5], o[6], 0.f);
    if (agg2p) {
        float di = dinv[i];
        float d2 = di * di;
        float4* ap = reinterpret_cast<float4*>(agg2p + (size_t)i * H2P);
        ap[0] = make_float4(o[0] * d2, o[1] * d2, o[2] * d2, o[3] * d2);
        ap[1] = make_float4(o[4] * d2, o[5] * d2, o[6] * d2, 0.f);
    }
}

// 4 rows/block; lane = 8 edge-slots x 8 features; fused log-softmax
__global__ __launch_bounds__(256) void k_agg2(const int* __restrict__ rowptr,
                                              const int* __restrict__ scol,
                                              const float* __restrict__ dinv,
                                              const float* __restrict__ h2p,
                                              const float* __restrict__ b2,
                                              float* __restrict__ out) {
    int row = blockIdx.x * 4 + (threadIdx.x >> 6);
    int L = threadIdx.x & 63;
    int ee = L >> 3, j = L & 7;
    int s = rowptr[row], eend = rowptr[row + 1];
    float dr = dinv[row];
    float acc = 0.f;
    for (int k = s + ee; k < eend; k += 8) {
        int c = scol[k];
        acc = fmaf(h2p[(size_t)c * H2P + j], dinv[c], acc);
    }
    acc += __shfl_xor(acc, 8, 64);
    acc += __shfl_xor(acc, 16, 64);
    acc += __shfl_xor(acc, 32, 64);
    acc += h2p[(size_t)row * H2P + j] * dr;
    float v = acc * dr + ((j < 7) ? b2[j] : 0.f);
    if (j == 7) v = -3.0e38f;
    float m = v;
    m = fmaxf(m, __shfl_xor(m, 1, 64));
    m = fmaxf(m, __shfl_xor(m, 2, 64));
    m = fmaxf(m, __shfl_xor(m, 4, 64));
    float ex = (j < 7) ? expf(v - m) : 0.f;
    float ssum = ex;
    ssum += __shfl_xor(ssum, 1, 64);
    ssum += __shfl_xor(ssum, 2, 64);
    ssum += __shfl_xor(ssum, 4, 64);
    float ls = logf(ssum);
    if (j < 7) out[(size_t)row * OUTD + j] = v - m - ls;
}

// ============================ fallback (small ws): atomic path ============================

__global__ void k_selfloop1(const float* __restrict__ h1, const float* __restrict__ dinv,
                            float* __restrict__ agg1) {
    int t = blockIdx.x * blockDim.x + threadIdx.x;
    if (t >= NN * HID) return;
    int i = t >> 4;
    float di = dinv[i];
    agg1[t] = h1[t] * di * di;
}

__global__ void k_scatter1f(const int* __restrict__ ei, const float* __restrict__ dinv,
                            const float* __restrict__ h1, float* __restrict__ agg1) {
    int t = blockIdx.x * blockDim.x + threadIdx.x;
    int e = t >> 4, j = t & 15;
    if (e >= EE) return;
    int r = ei[e], c = ei[EE + e];
    float nrm = dinv[r] * dinv[c];
    atomicAdd(&agg1[(size_t)r * HID + j], h1[(size_t)c * HID + j] * nrm);
}

__global__ void k_scatter2f(const int* __restrict__ ei, const float* __restrict__ dinv,
                            const float* __restrict__ h2p, float* __restrict__ agg2p) {
    int t = blockIdx.x * blockDim.x + threadIdx.x;
    int e = t >> 3, j = t & 7;
    if (e >= EE || j >= OUTD) return;
    int r = ei[e], c = ei[EE + e];
    float nrm = dinv[r] * dinv[c];
    atomicAdd(&agg2p[(size_t)r * H2P + j], h2p[(size_t)c * H2P + j] * nrm);
}

__global__ void k_logsoftmax(const float* __restrict__ agg2p, const float* __restrict__ b2,
                             float* __restrict__ out) {
    int i = blockIdx.x * blockDim.x + threadIdx.x;
    if (i >= NN) return;
    const float4* ap = reinterpret_cast<const float4*>(agg2p + (size_t)i * H2P);
    float4 a = ap[0], b = ap[1];
    float v[7] = {a.x, a.y, a.z, a.w, b.x, b.y, b.z};
#pragma unroll
    for (int j = 0; j < 7; ++j) v[j] += b2[j];
    float m = v[0];
#pragma unroll
    for (int j = 1; j < 7; ++j) m = fmaxf(m, v[j]);
    float ssum = 0.f;
#pragma unroll
    for (int j = 0; j < 7; ++j) ssum += expf(v[j] - m);
    float ls = logf(ssum);
#pragma unroll
    for (int j = 0; j < 7; ++j) out[(size_t)i * OUTD + j] = v[j] - m - ls;
}

// ============================ launch ============================

extern "C" void kernel_launch(void* const* d_in, const int* in_sizes, int n_in,
                              void* d_out, int out_size, void* d_ws, size_t ws_size,
                              hipStream_t stream) {
    const float* x  = (const float*)d_in[0];
    const int*   ei = (const int*)d_in[1];     // [2, E] flattened
    const float* W1 = (const float*)d_in[2];
    const float* b1 = (const float*)d_in[3];
    const float* W2 = (const float*)d_in[4];
    const float* b2 = (const float*)d_in[5];
    float* out = (float*)d_out;
    float* ws  = (float*)d_ws;

    float* dinv = ws;                       // N
    float* h1   = ws + NN;                  // 16N
    float* agg1 = ws + NN + 16 * NN;        // 16N
    float* h2p  = h1;                       // 8N, reuses dead h1

    const size_t need_csr = (size_t)(33 * NN) * 4 + (size_t)(3 * NN + 1 + EE) * 4;
    const bool csr = ws_size >= need_csr;

    if (csr) {
        int* ibase  = (int*)(ws + (size_t)33 * NN);
        int* cnt    = ibase;                 // N
        int* rowptr = ibase + NN;            // N+1
        int* cursor = ibase + 2 * NN + 1;    // N
        int* scol   = ibase + 3 * NN + 1;    // E

        hipLaunchKernelGGL(k_zero_i32, dim3((NN + 255) / 256), dim3(256), 0, stream, cnt, NN);
        hipLaunchKernelGGL(k_count, dim3((EE + 255) / 256), dim3(256), 0, stream, ei, cnt);
        hipLaunchKernelGGL(k_dinv_from_cnt, dim3((NN + 255) / 256), dim3(256), 0, stream,
                           cnt, dinv);
        hipLaunchKernelGGL(k_scan, dim3(1), dim3(1024), 0, stream, cnt, rowptr, cursor);
        hipLaunchKernelGGL(k_place, dim3((EE + 255) / 256), dim3(256), 0, stream,
                           ei, cursor, scol);
        hipLaunchKernelGGL(k_gemm1, dim3((NN + RB - 1) / RB), dim3(256), 0, stream,
                           x, W1, h1);
        hipLaunchKernelGGL(k_agg1, dim3(NN / 4), dim3(256), 0, stream,
                           rowptr, scol, dinv, h1, agg1);
        hipLaunchKernelGGL(k_mlp2, dim3((NN + 255) / 256), dim3(256), 0, stream,
                           agg1, b1, W2, dinv, h2p, (float*)nullptr);
        hipLaunchKernelGGL(k_agg2, dim3(NN / 4), dim3(256), 0, stream,
                           rowptr, scol, dinv, h2p, b2, out);
    } else {
        // atomic fallback (R1-proven): needs 33N floats + N ints
        float* agg2p = h1 + 8 * NN;
        int* cnt = (int*)agg1;               // dead until after k_dinv_from_cnt
        hipLaunchKernelGGL(k_zero_i32, dim3((NN + 255) / 256), dim3(256), 0, stream, cnt, NN);
        hipLaunchKernelGGL(k_count, dim3((EE + 255) / 256), dim3(256), 0, stream, ei, cnt);
        hipLaunchKernelGGL(k_dinv_from_cnt, dim3((NN + 255) / 256), dim3(256), 0, stream,
                           cnt, dinv);
        hipLaunchKernelGGL(k_gemm1, dim3((NN + RB - 1) / RB), dim3(256), 0, stream,
                           x, W1, h1);
        hipLaunchKernelGGL(k_selfloop1, dim3((NN * HID + 255) / 256), dim3(256), 0, stream,
                           h1, dinv, agg1);
        hipLaunchKernelGGL(k_scatter1f, dim3((EE * HID) / 256), dim3(256), 0, stream,
                           ei, dinv, h1, agg1);
        hipLaunchKernelGGL(k_mlp2, dim3((NN + 255) / 256), dim3(256), 0, stream,
                           agg1, b1, W2, dinv, h2p, agg2p);
        hipLaunchKernelGGL(k_scatter2f, dim3((EE * 8) / 256), dim3(256), 0, stream,
                           ei, dinv, h2p, agg2p);
        hipLaunchKernelGGL(k_logsoftmax, dim3((NN + 255) / 256), dim3(256), 0, stream,
                           agg2p, b2, out);
    }
}

// Round 4
// 646.449 us; speedup vs baseline: 6.7253x; 1.3377x over previous
//
#include <hip/hip_runtime.h>

#define NN   100000
#define EE   3200000
#define KDIM 1433
#define HID  16
#define H2P  8
#define OUTD 7

// ---- gemm1 tiling ----
#define KC    128
#define RB    64
#define XSTR  133            // lane stride 133 mod 32 = 5 (odd) -> 2-way LDS aliasing = free
#define NCHUNK ((KDIM + KC - 1) / KC)   // 12

// ============================ degree / norm ============================

__global__ void k_zero_i32(int* __restrict__ p, int n) {
    int i = blockIdx.x * blockDim.x + threadIdx.x;
    if (i < n) p[i] = 0;
}

__global__ void k_count(const int* __restrict__ ei, int* __restrict__ cnt) {
    int e = blockIdx.x * blockDim.x + threadIdx.x;
    if (e < EE) atomicAdd(&cnt[ei[e]], 1);      // row = ei[0][e]
}

__global__ void k_dinv_from_cnt(const int* __restrict__ cnt, float* __restrict__ dinv) {
    int i = blockIdx.x * blockDim.x + threadIdx.x;
    if (i < NN) dinv[i] = rsqrtf((float)cnt[i] + 1.0f);   // +1 self-loop
}

// single-block exclusive scan of cnt[NN] -> rowptr[NN+1], cursor[NN]
__global__ __launch_bounds__(1024) void k_scan(const int* __restrict__ cnt,
                                               int* __restrict__ rowptr,
                                               int* __restrict__ cursor) {
    __shared__ int spart[16];
    __shared__ int soff_s;
    const int tid = threadIdx.x;
    const int L = tid & 63;
    const int w = tid >> 6;
    if (tid == 0) soff_s = 0;
    __syncthreads();
    for (int base = 0; base < NN; base += 4096) {
        int i0 = base + tid * 4;
        int v0 = (i0 + 0 < NN) ? cnt[i0 + 0] : 0;
        int v1 = (i0 + 1 < NN) ? cnt[i0 + 1] : 0;
        int v2 = (i0 + 2 < NN) ? cnt[i0 + 2] : 0;
        int v3 = (i0 + 3 < NN) ? cnt[i0 + 3] : 0;
        int local = v0 + v1 + v2 + v3;
        int s = local;
#pragma unroll
        for (int ofs = 1; ofs < 64; ofs <<= 1) {
            int n = __shfl_up(s, ofs, 64);
            if (L >= ofs) s += n;
        }
        if (L == 63) spart[w] = s;
        __syncthreads();
        if (w == 0) {
            int p = (L < 16) ? spart[L] : 0;
#pragma unroll
            for (int ofs = 1; ofs < 16; ofs <<= 1) {
                int n = __shfl_up(p, ofs, 64);
                if (L >= ofs) p += n;
            }
            if (L < 16) spart[L] = p;
        }
        __syncthreads();
        int waveoff = (w > 0) ? spart[w - 1] : 0;
        int excl = soff_s + waveoff + s - local;
        if (i0 + 0 < NN) { rowptr[i0 + 0] = excl; cursor[i0 + 0] = excl; excl += v0; }
        if (i0 + 1 < NN) { rowptr[i0 + 1] = excl; cursor[i0 + 1] = excl; excl += v1; }
        if (i0 + 2 < NN) { rowptr[i0 + 2] = excl; cursor[i0 + 2] = excl; excl += v2; }
        if (i0 + 3 < NN) { rowptr[i0 + 3] = excl; cursor[i0 + 3] = excl; excl += v3; }
        __syncthreads();
        if (tid == 0) soff_s += spart[15];
        __syncthreads();
    }
    if (tid == 0) rowptr[NN] = soff_s;
}

__global__ void k_place(const int* __restrict__ ei, int* __restrict__ cursor,
                        int* __restrict__ scol) {
    int e = blockIdx.x * blockDim.x + threadIdx.x;
    if (e >= EE) return;
    int r = ei[e], c = ei[EE + e];
    int p = atomicAdd(&cursor[r], 1);
    scol[p] = c;
}

// ============================ layer 1 GEMM ============================

// h1[N][16] = x[N][1433] @ W1[1433][16]
// Staging goes through an explicit register batch (tmp[32]) so all 32 global
// loads are in flight concurrently (one vmcnt drain per chunk, not per element).
__global__ __launch_bounds__(256) void k_gemm1(const float* __restrict__ x,
                                               const float* __restrict__ W1,
                                               float* __restrict__ h1) {
    __shared__ __align__(16) float xs[RB * XSTR];   // 34 KB -> 4 blocks/CU (LDS-limited)
    const int tid = threadIdx.x;
    const int wu  = __builtin_amdgcn_readfirstlane(tid >> 6);  // W1 loads -> s_load
    const int L   = tid & 63;
    const int r0  = blockIdx.x * RB;

    // staging coords: thread owns column kk, rows rbase+2m (m=0..31)
    const int kk    = tid & 127;
    const int rbase = tid >> 7;              // 0 or 1
    const bool rowok0 = (r0 + rbase) < NN;   // whole block in-range except last

    float acc[HID];
#pragma unroll
    for (int j = 0; j < HID; ++j) acc[j] = 0.f;

    for (int c = 0; c < NCHUNK; ++c) {
        const int c0 = c * KC;
        const int kvalid = (KDIM - c0 < KC) ? (KDIM - c0) : KC;
        const bool kok = kk < kvalid;

        // ---- issue all 32 independent loads (overlaps prior chunk's compute) ----
        float tmp[32];
        const float* xp = x + (size_t)(r0 + rbase) * KDIM + c0 + kk;
#pragma unroll
        for (int m = 0; m < 32; ++m) {
            int gr = r0 + rbase + 2 * m;
            tmp[m] = (kok && (gr < NN)) ? xp[(size_t)(2 * m) * KDIM] : 0.f;
        }
        __syncthreads();                     // xs free (prev compute done)
#pragma unroll
        for (int m = 0; m < 32; ++m) {
            xs[(rbase + 2 * m) * XSTR + kk] = tmp[m];
        }
        __syncthreads();

        // ---- compute: wave wu covers kk in [wu*32, wu*32+32) ----
        int kend = kvalid - wu * 32;
        kend = kend < 0 ? 0 : (kend > 32 ? 32 : kend);
        const float* wbase = W1 + (size_t)(c0 + wu * 32) * HID;
        const float* xbase = xs + L * XSTR + wu * 32;
#pragma unroll 4
        for (int i = 0; i < kend; ++i) {
            float xv = xbase[i];
            const float* wr = wbase + i * HID;
#pragma unroll
            for (int j = 0; j < HID; ++j) acc[j] = fmaf(xv, wr[j], acc[j]);
        }
    }
    __syncthreads();
    float4* red4 = reinterpret_cast<float4*>(xs);
    red4[(wu * 64 + L) * 4 + 0] = make_float4(acc[0], acc[1], acc[2], acc[3]);
    red4[(wu * 64 + L) * 4 + 1] = make_float4(acc[4], acc[5], acc[6], acc[7]);
    red4[(wu * 64 + L) * 4 + 2] = make_float4(acc[8], acc[9], acc[10], acc[11]);
    red4[(wu * 64 + L) * 4 + 3] = make_float4(acc[12], acc[13], acc[14], acc[15]);
    __syncthreads();
    int rr = tid >> 2, jj = tid & 3;
    float4 a = red4[(0 * 64 + rr) * 4 + jj];
    float4 b = red4[(1 * 64 + rr) * 4 + jj];
    float4 cfr = red4[(2 * 64 + rr) * 4 + jj];
    float4 d = red4[(3 * 64 + rr) * 4 + jj];
    float4 s = make_float4(a.x + b.x + cfr.x + d.x, a.y + b.y + cfr.y + d.y,
                           a.z + b.z + cfr.z + d.z, a.w + b.w + cfr.w + d.w);
    int gr = r0 + rr;
    if (gr < NN) reinterpret_cast<float4*>(h1)[(size_t)gr * 4 + jj] = s;
}

// ============================ CSR gather aggregation ============================

// 4 rows/block (1 wave each). lane = 16 edge-slots x 4 float4-quarters.
__global__ __launch_bounds__(256) void k_agg1(const int* __restrict__ rowptr,
                                              const int* __restrict__ scol,
                                              const float* __restrict__ dinv,
                                              const float* __restrict__ h1,
                                              float* __restrict__ agg1) {
    int row = blockIdx.x * 4 + (threadIdx.x >> 6);
    int L = threadIdx.x & 63;
    int ee = L >> 2;        // 0..15 edge slot
    int q  = L & 3;         // float4 quarter of the 16-float row
    int s = rowptr[row], eend = rowptr[row + 1];
    float dr = dinv[row];
    const float4* h4 = reinterpret_cast<const float4*>(h1);
    float4 acc = make_float4(0.f, 0.f, 0.f, 0.f);
    for (int k = s + ee; k < eend; k += 16) {
        int c = scol[k];
        float dc = dinv[c];
        float4 hv = h4[(size_t)c * 4 + q];
        acc.x = fmaf(hv.x, dc, acc.x);
        acc.y = fmaf(hv.y, dc, acc.y);
        acc.z = fmaf(hv.z, dc, acc.z);
        acc.w = fmaf(hv.w, dc, acc.w);
    }
#pragma unroll
    for (int mask = 4; mask <= 32; mask <<= 1) {
        acc.x += __shfl_xor(acc.x, mask, 64);
        acc.y += __shfl_xor(acc.y, mask, 64);
        acc.z += __shfl_xor(acc.z, mask, 64);
        acc.w += __shfl_xor(acc.w, mask, 64);
    }
    float4 sv = h4[(size_t)row * 4 + q];
    acc.x = (acc.x + sv.x * dr) * dr;
    acc.y = (acc.y + sv.y * dr) * dr;
    acc.z = (acc.z + sv.z * dr) * dr;
    acc.w = (acc.w + sv.w * dr) * dr;
    if (L < 4) reinterpret_cast<float4*>(agg1)[(size_t)row * 4 + q] = acc;
}

// h2p[i][0..8) = relu(agg1[i]+b1) @ W2 (padded to 8)
__global__ void k_mlp2(const float* __restrict__ agg1, const float* __restrict__ b1,
                       const float* __restrict__ W2, const float* __restrict__ dinv,
                       float* __restrict__ h2p, float* __restrict__ agg2p) {
    int i = blockIdx.x * blockDim.x + threadIdx.x;
    if (i >= NN) return;
    const float4* a4 = reinterpret_cast<const float4*>(agg1 + (size_t)i * HID);
    float4 t0 = a4[0], t1 = a4[1], t2 = a4[2], t3 = a4[3];
    float v[16] = {t0.x, t0.y, t0.z, t0.w, t1.x, t1.y, t1.z, t1.w,
                   t2.x, t2.y, t2.z, t2.w, t3.x, t3.y, t3.z, t3.w};
#pragma unroll
    for (int k = 0; k < 16; ++k) v[k] = fmaxf(v[k] + b1[k], 0.f);
    float o[8] = {0.f, 0.f, 0.f, 0.f, 0.f, 0.f, 0.f, 0.f};
#pragma unroll
    for (int k = 0; k < 16; ++k)
#pragma unroll
        for (int j = 0; j < 7; ++j) o[j] = fmaf(v[k], W2[k * 7 + j], o[j]);
    float4* hp = reinterpret_cast<float4*>(h2p + (size_t)i * H2P);
    hp[0] = make_float4(o[0], o[1], o[2], o[3]);
    hp[1] = make_float4(o[4], o[5], o[6], 0.f);
    if (agg2p) {
        float di = dinv[i];
        float d2 = di * di;
        float4* ap = reinterpret_cast<float4*>(agg2p + (size_t)i * H2P);
        ap[0] = make_float4(o[0] * d2, o[1] * d2, o[2] * d2, o[3] * d2);
        ap[1] = make_float4(o[4] * d2, o[5] * d2, o[6] * d2, 0.f);
    }
}

// 4 rows/block; lane = 8 edge-slots x 8 features; fused log-softmax
__global__ __launch_bounds__(256) void k_agg2(const int* __restrict__ rowptr,
                                              const int* __restrict__ scol,
                                              const float* __restrict__ dinv,
                                              const float* __restrict__ h2p,
                                              const float* __restrict__ b2,
                                              float* __restrict__ out) {
    int row = blockIdx.x * 4 + (threadIdx.x >> 6);
    int L = threadIdx.x & 63;
    int ee = L >> 3, j = L & 7;
    int s = rowptr[row], eend = rowptr[row + 1];
    float dr = dinv[row];
    float acc = 0.f;
    for (int k = s + ee; k < eend; k += 8) {
        int c = scol[k];
        acc = fmaf(h2p[(size_t)c * H2P + j], dinv[c], acc);
    }
    acc += __shfl_xor(acc, 8, 64);
    acc += __shfl_xor(acc, 16, 64);
    acc += __shfl_xor(acc, 32, 64);
    acc += h2p[(size_t)row * H2P + j] * dr;
    float v = acc * dr + ((j < 7) ? b2[j] : 0.f);
    if (j == 7) v = -3.0e38f;
    float m = v;
    m = fmaxf(m, __shfl_xor(m, 1, 64));
    m = fmaxf(m, __shfl_xor(m, 2, 64));
    m = fmaxf(m, __shfl_xor(m, 4, 64));
    float ex = (j < 7) ? expf(v - m) : 0.f;
    float ssum = ex;
    ssum += __shfl_xor(ssum, 1, 64);
    ssum += __shfl_xor(ssum, 2, 64);
    ssum += __shfl_xor(ssum, 4, 64);
    float ls = logf(ssum);
    if (j < 7) out[(size_t)row * OUTD + j] = v - m - ls;
}

// ============================ fallback (small ws): atomic path ============================

__global__ void k_selfloop1(const float* __restrict__ h1, const float* __restrict__ dinv,
                            float* __restrict__ agg1) {
    int t = blockIdx.x * blockDim.x + threadIdx.x;
    if (t >= NN * HID) return;
    int i = t >> 4;
    float di = dinv[i];
    agg1[t] = h1[t] * di * di;
}

__global__ void k_scatter1f(const int* __restrict__ ei, const float* __restrict__ dinv,
                            const float* __restrict__ h1, float* __restrict__ agg1) {
    int t = blockIdx.x * blockDim.x + threadIdx.x;
    int e = t >> 4, j = t & 15;
    if (e >= EE) return;
    int r = ei[e], c = ei[EE + e];
    float nrm = dinv[r] * dinv[c];
    atomicAdd(&agg1[(size_t)r * HID + j], h1[(size_t)c * HID + j] * nrm);
}

__global__ void k_scatter2f(const int* __restrict__ ei, const float* __restrict__ dinv,
                            const float* __restrict__ h2p, float* __restrict__ agg2p) {
    int t = blockIdx.x * blockDim.x + threadIdx.x;
    int e = t >> 3, j = t & 7;
    if (e >= EE || j >= OUTD) return;
    int r = ei[e], c = ei[EE + e];
    float nrm = dinv[r] * dinv[c];
    atomicAdd(&agg2p[(size_t)r * H2P + j], h2p[(size_t)c * H2P + j] * nrm);
}

__global__ void k_logsoftmax(const float* __restrict__ agg2p, const float* __restrict__ b2,
                             float* __restrict__ out) {
    int i = blockIdx.x * blockDim.x + threadIdx.x;
    if (i >= NN) return;
    const float4* ap = reinterpret_cast<const float4*>(agg2p + (size_t)i * H2P);
    float4 a = ap[0], b = ap[1];
    float v[7] = {a.x, a.y, a.z, a.w, b.x, b.y, b.z};
#pragma unroll
    for (int j = 0; j < 7; ++j) v[j] += b2[j];
    float m = v[0];
#pragma unroll
    for (int j = 1; j < 7; ++j) m = fmaxf(m, v[j]);
    float ssum = 0.f;
#pragma unroll
    for (int j = 0; j < 7; ++j) ssum += expf(v[j] - m);
    float ls = logf(ssum);
#pragma unroll
    for (int j = 0; j < 7; ++j) out[(size_t)i * OUTD + j] = v[j] - m - ls;
}

// ============================ launch ============================

extern "C" void kernel_launch(void* const* d_in, const int* in_sizes, int n_in,
                              void* d_out, int out_size, void* d_ws, size_t ws_size,
                              hipStream_t stream) {
    const float* x  = (const float*)d_in[0];
    const int*   ei = (const int*)d_in[1];     // [2, E] flattened
    const float* W1 = (const float*)d_in[2];
    const float* b1 = (const float*)d_in[3];
    const float* W2 = (const float*)d_in[4];
    const float* b2 = (const float*)d_in[5];
    float* out = (float*)d_out;
    float* ws  = (float*)d_ws;

    float* dinv = ws;                       // N
    float* h1   = ws + NN;                  // 16N
    float* agg1 = ws + NN + 16 * NN;        // 16N
    float* h2p  = h1;                       // 8N, reuses dead h1

    const size_t need_csr = (size_t)(33 * NN) * 4 + (size_t)(3 * NN + 1 + EE) * 4;
    const bool csr = ws_size >= need_csr;

    if (csr) {
        int* ibase  = (int*)(ws + (size_t)33 * NN);
        int* cnt    = ibase;                 // N
        int* rowptr = ibase + NN;            // N+1
        int* cursor = ibase + 2 * NN + 1;    // N
        int* scol   = ibase + 3 * NN + 1;    // E

        hipLaunchKernelGGL(k_zero_i32, dim3((NN + 255) / 256), dim3(256), 0, stream, cnt, NN);
        hipLaunchKernelGGL(k_count, dim3((EE + 255) / 256), dim3(256), 0, stream, ei, cnt);
        hipLaunchKernelGGL(k_dinv_from_cnt, dim3((NN + 255) / 256), dim3(256), 0, stream,
                           cnt, dinv);
        hipLaunchKernelGGL(k_scan, dim3(1), dim3(1024), 0, stream, cnt, rowptr, cursor);
        hipLaunchKernelGGL(k_place, dim3((EE + 255) / 256), dim3(256), 0, stream,
                           ei, cursor, scol);
        hipLaunchKernelGGL(k_gemm1, dim3((NN + RB - 1) / RB), dim3(256), 0, stream,
                           x, W1, h1);
        hipLaunchKernelGGL(k_agg1, dim3(NN / 4), dim3(256), 0, stream,
                           rowptr, scol, dinv, h1, agg1);
        hipLaunchKernelGGL(k_mlp2, dim3((NN + 255) / 256), dim3(256), 0, stream,
                           agg1, b1, W2, dinv, h2p, (float*)nullptr);
        hipLaunchKernelGGL(k_agg2, dim3(NN / 4), dim3(256), 0, stream,
                           rowptr, scol, dinv, h2p, b2, out);
    } else {
        // atomic fallback (R1-proven): needs 33N floats + N ints
        float* agg2p = h1 + 8 * NN;
        int* cnt = (int*)agg1;               // dead until after k_dinv_from_cnt
        hipLaunchKernelGGL(k_zero_i32, dim3((NN + 255) / 256), dim3(256), 0, stream, cnt, NN);
        hipLaunchKernelGGL(k_count, dim3((EE + 255) / 256), dim3(256), 0, stream, ei, cnt);
        hipLaunchKernelGGL(k_dinv_from_cnt, dim3((NN + 255) / 256), dim3(256), 0, stream,
                           cnt, dinv);
        hipLaunchKernelGGL(k_gemm1, dim3((NN + RB - 1) / RB), dim3(256), 0, stream,
                           x, W1, h1);
        hipLaunchKernelGGL(k_selfloop1, dim3((NN * HID + 255) / 256), dim3(256), 0, stream,
                           h1, dinv, agg1);
        hipLaunchKernelGGL(k_scatter1f, dim3((EE * HID) / 256), dim3(256), 0, stream,
                           ei, dinv, h1, agg1);
        hipLaunchKernelGGL(k_mlp2, dim3((NN + 255) / 256), dim3(256), 0, stream,
                           agg1, b1, W2, dinv, h2p, agg2p);
        hipLaunchKernelGGL(k_scatter2f, dim3((EE * 8) / 256), dim3(256), 0, stream,
                           ei, dinv, h2p, agg2p);
        hipLaunchKernelGGL(k_logsoftmax, dim3((NN + 255) / 256), dim3(256), 0, stream,
                           agg2p, b2, out);
    }
}

// Round 5
// 584.761 us; speedup vs baseline: 7.4348x; 1.1055x over previous
//
#include <hip/hip_runtime.h>

#define NN   100000
#define EE   3200000
#define KDIM 1433
#define HID  16
#define H2P  8
#define OUTD 7

// ---- gemm1 tiling ----
#define KC    128
#define RB    64
#define XSTR  133            // lane stride 133 mod 32 = 5 (odd) -> 2-way LDS aliasing = free
#define NCHUNK ((KDIM + KC - 1) / KC)   // 12

// ---- scan tiling ----
#define SCAN_TPB   1024
#define SCAN_ELEMS 4096
#define NB_SCAN    ((NN + SCAN_ELEMS - 1) / SCAN_ELEMS)   // 25

// ============================ degree / norm ============================

__global__ void k_zero_i32(int* __restrict__ p, int n) {
    int i = blockIdx.x * blockDim.x + threadIdx.x;
    if (i < n) p[i] = 0;
}

__global__ void k_count(const int* __restrict__ ei, int* __restrict__ cnt) {
    int e = blockIdx.x * blockDim.x + threadIdx.x;
    if (e < EE) atomicAdd(&cnt[ei[e]], 1);      // row = ei[0][e]
}

__global__ void k_dinv_from_cnt(const int* __restrict__ cnt, float* __restrict__ dinv) {
    int i = blockIdx.x * blockDim.x + threadIdx.x;
    if (i < NN) dinv[i] = rsqrtf((float)cnt[i] + 1.0f);   // +1 self-loop
}

// ---- 3-phase parallel scan: per-block scan -> scan block sums -> add offsets ----

__global__ __launch_bounds__(SCAN_TPB) void k_scan1(const int* __restrict__ cnt,
                                                    int* __restrict__ rowptr,
                                                    int* __restrict__ bsum) {
    __shared__ int spart[16];
    const int tid = threadIdx.x;
    const int L = tid & 63;
    const int w = tid >> 6;
    const int i0 = blockIdx.x * SCAN_ELEMS + tid * 4;
    int v0 = (i0 + 0 < NN) ? cnt[i0 + 0] : 0;
    int v1 = (i0 + 1 < NN) ? cnt[i0 + 1] : 0;
    int v2 = (i0 + 2 < NN) ? cnt[i0 + 2] : 0;
    int v3 = (i0 + 3 < NN) ? cnt[i0 + 3] : 0;
    int local = v0 + v1 + v2 + v3;
    int s = local;
#pragma unroll
    for (int ofs = 1; ofs < 64; ofs <<= 1) {
        int n = __shfl_up(s, ofs, 64);
        if (L >= ofs) s += n;
    }
    if (L == 63) spart[w] = s;
    __syncthreads();
    if (w == 0) {
        int p = (L < 16) ? spart[L] : 0;
#pragma unroll
        for (int ofs = 1; ofs < 16; ofs <<= 1) {
            int n = __shfl_up(p, ofs, 64);
            if (L >= ofs) p += n;
        }
        if (L < 16) spart[L] = p;
    }
    __syncthreads();
    int waveoff = (w > 0) ? spart[w - 1] : 0;
    int excl = waveoff + s - local;                 // block-local exclusive
    if (i0 + 0 < NN) { rowptr[i0 + 0] = excl; excl += v0; }
    if (i0 + 1 < NN) { rowptr[i0 + 1] = excl; excl += v1; }
    if (i0 + 2 < NN) { rowptr[i0 + 2] = excl; excl += v2; }
    if (i0 + 3 < NN) { rowptr[i0 + 3] = excl; excl += v3; }
    if (tid == 0) bsum[blockIdx.x] = spart[15];
}

__global__ void k_scan2(const int* __restrict__ bsum, int* __restrict__ boffs,
                        int* __restrict__ rowptr) {
    int L = threadIdx.x;   // one wave
    int v = (L < NB_SCAN) ? bsum[L] : 0;
    int s = v;
#pragma unroll
    for (int ofs = 1; ofs < 64; ofs <<= 1) {
        int n = __shfl_up(s, ofs, 64);
        if (L >= ofs) s += n;
    }
    if (L < NB_SCAN) boffs[L] = s - v;
    if (L == NB_SCAN - 1) rowptr[NN] = s;          // grand total (=EE)
}

__global__ __launch_bounds__(SCAN_TPB) void k_scan3(const int* __restrict__ boffs,
                                                    int* __restrict__ rowptr,
                                                    int* __restrict__ cursor) {
    const int off = boffs[blockIdx.x];
    const int i0 = blockIdx.x * SCAN_ELEMS + threadIdx.x * 4;
#pragma unroll
    for (int t = 0; t < 4; ++t) {
        int i = i0 + t;
        if (i < NN) {
            int v = rowptr[i] + off;
            rowptr[i] = v;
            cursor[i] = v;
        }
    }
}

__global__ void k_place(const int* __restrict__ ei, int* __restrict__ cursor,
                        int* __restrict__ scol) {
    int e = blockIdx.x * blockDim.x + threadIdx.x;
    if (e >= EE) return;
    int r = ei[e], c = ei[EE + e];
    int p = atomicAdd(&cursor[r], 1);
    scol[p] = c;
}

// ============================ layer 1 GEMM ============================

// h1[N][16] = x[N][1433] @ W1[1433][16]
// Software-pipelined staging: chunk c+1's 32 independent loads are issued right
// after chunk c's LDS write, so HBM latency hides under chunk c's FMA phase.
__global__ __launch_bounds__(256) void k_gemm1(const float* __restrict__ x,
                                               const float* __restrict__ W1,
                                               float* __restrict__ h1) {
    __shared__ __align__(16) float xs[RB * XSTR];   // 34 KB
    const int tid = threadIdx.x;
    const int wu  = __builtin_amdgcn_readfirstlane(tid >> 6);  // W1 loads -> s_load
    const int L   = tid & 63;
    const int r0  = blockIdx.x * RB;

    const int kk    = tid & 127;
    const int rbase = tid >> 7;              // 0 or 1
    const bool fullrows = (r0 + RB) <= NN;

    float tmp[32];
    float acc[HID];
#pragma unroll
    for (int j = 0; j < HID; ++j) acc[j] = 0.f;

    // ---- prologue: issue chunk 0 loads (kvalid = 128, kk always ok) ----
    {
        const float* xp = x + (size_t)(r0 + rbase) * KDIM + kk;
        if (fullrows) {
#pragma unroll
            for (int m = 0; m < 32; ++m) tmp[m] = xp[(size_t)(2 * m) * KDIM];
        } else {
#pragma unroll
            for (int m = 0; m < 32; ++m) {
                int gr = r0 + rbase + 2 * m;
                tmp[m] = (gr < NN) ? xp[(size_t)(2 * m) * KDIM] : 0.f;
            }
        }
    }

    for (int c = 0; c < NCHUNK; ++c) {
        const int c0 = c * KC;
        const int kvalid = (KDIM - c0 < KC) ? (KDIM - c0) : KC;
        __syncthreads();                     // prev compute done, xs free
#pragma unroll
        for (int m = 0; m < 32; ++m) {       // vmcnt drain happens here
            xs[(rbase + 2 * m) * XSTR + kk] = tmp[m];
        }
        __syncthreads();

        // ---- prefetch chunk c+1 (overlaps the compute below) ----
        if (c + 1 < NCHUNK) {
            const int c0n = c0 + KC;
            const int kvn = KDIM - c0n;
            const float* xp = x + (size_t)(r0 + rbase) * KDIM + c0n + kk;
            if (fullrows && kvn >= KC) {
#pragma unroll
                for (int m = 0; m < 32; ++m) tmp[m] = xp[(size_t)(2 * m) * KDIM];
            } else {
                const bool kokn = kk < kvn;
#pragma unroll
                for (int m = 0; m < 32; ++m) {
                    int gr = r0 + rbase + 2 * m;
                    tmp[m] = (kokn && gr < NN) ? xp[(size_t)(2 * m) * KDIM] : 0.f;
                }
            }
        }

        // ---- compute: wave wu covers kk in [wu*32, wu*32+32) ----
        int kend = kvalid - wu * 32;
        kend = kend < 0 ? 0 : (kend > 32 ? 32 : kend);
        const float* wbase = W1 + (size_t)(c0 + wu * 32) * HID;
        const float* xbase = xs + L * XSTR + wu * 32;
#pragma unroll 4
        for (int i = 0; i < kend; ++i) {
            float xv = xbase[i];
            const float* wr = wbase + i * HID;
#pragma unroll
            for (int j = 0; j < HID; ++j) acc[j] = fmaf(xv, wr[j], acc[j]);
        }
    }
    __syncthreads();
    float4* red4 = reinterpret_cast<float4*>(xs);
    red4[(wu * 64 + L) * 4 + 0] = make_float4(acc[0], acc[1], acc[2], acc[3]);
    red4[(wu * 64 + L) * 4 + 1] = make_float4(acc[4], acc[5], acc[6], acc[7]);
    red4[(wu * 64 + L) * 4 + 2] = make_float4(acc[8], acc[9], acc[10], acc[11]);
    red4[(wu * 64 + L) * 4 + 3] = make_float4(acc[12], acc[13], acc[14], acc[15]);
    __syncthreads();
    int rr = tid >> 2, jj = tid & 3;
    float4 a = red4[(0 * 64 + rr) * 4 + jj];
    float4 b = red4[(1 * 64 + rr) * 4 + jj];
    float4 cfr = red4[(2 * 64 + rr) * 4 + jj];
    float4 d = red4[(3 * 64 + rr) * 4 + jj];
    float4 s = make_float4(a.x + b.x + cfr.x + d.x, a.y + b.y + cfr.y + d.y,
                           a.z + b.z + cfr.z + d.z, a.w + b.w + cfr.w + d.w);
    int gr = r0 + rr;
    if (gr < NN) reinterpret_cast<float4*>(h1)[(size_t)gr * 4 + jj] = s;
}

// ============================ fused CSR aggregation + layer-2 matvec ============================

// 4 rows/block (1 wave each). lane = 16 edge-slots x 4 float4-quarters.
// After the reduce, the full 16-vector is assembled in-wave via shuffles and the
// relu + 16x7 matvec runs immediately (replaces the separate k_mlp2 pass).
__global__ __launch_bounds__(256) void k_agg1m(const int* __restrict__ rowptr,
                                               const int* __restrict__ scol,
                                               const float* __restrict__ dinv,
                                               const float* __restrict__ h1,
                                               const float* __restrict__ b1,
                                               const float* __restrict__ W2,
                                               float* __restrict__ h2p) {
    int row = blockIdx.x * 4 + (threadIdx.x >> 6);
    int L = threadIdx.x & 63;
    int ee = L >> 2;        // 0..15 edge slot
    int q  = L & 3;         // float4 quarter of the 16-float row
    int s = rowptr[row], eend = rowptr[row + 1];
    float dr = dinv[row];
    const float4* h4 = reinterpret_cast<const float4*>(h1);
    float4 acc = make_float4(0.f, 0.f, 0.f, 0.f);
    for (int k = s + ee; k < eend; k += 16) {
        int c = scol[k];
        float dc = dinv[c];
        float4 hv = h4[(size_t)c * 4 + q];
        acc.x = fmaf(hv.x, dc, acc.x);
        acc.y = fmaf(hv.y, dc, acc.y);
        acc.z = fmaf(hv.z, dc, acc.z);
        acc.w = fmaf(hv.w, dc, acc.w);
    }
#pragma unroll
    for (int mask = 4; mask <= 32; mask <<= 1) {
        acc.x += __shfl_xor(acc.x, mask, 64);
        acc.y += __shfl_xor(acc.y, mask, 64);
        acc.z += __shfl_xor(acc.z, mask, 64);
        acc.w += __shfl_xor(acc.w, mask, 64);
    }
    float4 sv = h4[(size_t)row * 4 + q];
    acc.x = (acc.x + sv.x * dr) * dr;
    acc.y = (acc.y + sv.y * dr) * dr;
    acc.z = (acc.z + sv.z * dr) * dr;
    acc.w = (acc.w + sv.w * dr) * dr;
    // assemble the full 16-vector in every lane (quarter qq lives in lane (L&~3)|qq)
    float v[16];
#pragma unroll
    for (int qq = 0; qq < 4; ++qq) {
        int src = (L & ~3) | qq;
        v[qq * 4 + 0] = __shfl(acc.x, src, 64);
        v[qq * 4 + 1] = __shfl(acc.y, src, 64);
        v[qq * 4 + 2] = __shfl(acc.z, src, 64);
        v[qq * 4 + 3] = __shfl(acc.w, src, 64);
    }
#pragma unroll
    for (int k = 0; k < 16; ++k) v[k] = fmaxf(v[k] + b1[k], 0.f);
    if (L < 8) {
        int j = (L < 7) ? L : 0;
        float o = 0.f;
#pragma unroll
        for (int k = 0; k < 16; ++k) o = fmaf(v[k], W2[k * 7 + j], o);
        h2p[(size_t)row * H2P + L] = (L < 7) ? o : 0.f;
    }
}

// 4 rows/block; lane = 8 edge-slots x 8 features; fused log-softmax
__global__ __launch_bounds__(256) void k_agg2(const int* __restrict__ rowptr,
                                              const int* __restrict__ scol,
                                              const float* __restrict__ dinv,
                                              const float* __restrict__ h2p,
                                              const float* __restrict__ b2,
                                              float* __restrict__ out) {
    int row = blockIdx.x * 4 + (threadIdx.x >> 6);
    int L = threadIdx.x & 63;
    int ee = L >> 3, j = L & 7;
    int s = rowptr[row], eend = rowptr[row + 1];
    float dr = dinv[row];
    float acc = 0.f;
    for (int k = s + ee; k < eend; k += 8) {
        int c = scol[k];
        acc = fmaf(h2p[(size_t)c * H2P + j], dinv[c], acc);
    }
    acc += __shfl_xor(acc, 8, 64);
    acc += __shfl_xor(acc, 16, 64);
    acc += __shfl_xor(acc, 32, 64);
    acc += h2p[(size_t)row * H2P + j] * dr;
    float v = acc * dr + ((j < 7) ? b2[j] : 0.f);
    if (j == 7) v = -3.0e38f;
    float m = v;
    m = fmaxf(m, __shfl_xor(m, 1, 64));
    m = fmaxf(m, __shfl_xor(m, 2, 64));
    m = fmaxf(m, __shfl_xor(m, 4, 64));
    float ex = (j < 7) ? expf(v - m) : 0.f;
    float ssum = ex;
    ssum += __shfl_xor(ssum, 1, 64);
    ssum += __shfl_xor(ssum, 2, 64);
    ssum += __shfl_xor(ssum, 4, 64);
    float ls = logf(ssum);
    if (j < 7) out[(size_t)row * OUTD + j] = v - m - ls;
}

// ============================ fallback (small ws): atomic path ============================

__global__ void k_selfloop1(const float* __restrict__ h1, const float* __restrict__ dinv,
                            float* __restrict__ agg1) {
    int t = blockIdx.x * blockDim.x + threadIdx.x;
    if (t >= NN * HID) return;
    int i = t >> 4;
    float di = dinv[i];
    agg1[t] = h1[t] * di * di;
}

__global__ void k_scatter1f(const int* __restrict__ ei, const float* __restrict__ dinv,
                            const float* __restrict__ h1, float* __restrict__ agg1) {
    int t = blockIdx.x * blockDim.x + threadIdx.x;
    int e = t >> 4, j = t & 15;
    if (e >= EE) return;
    int r = ei[e], c = ei[EE + e];
    float nrm = dinv[r] * dinv[c];
    atomicAdd(&agg1[(size_t)r * HID + j], h1[(size_t)c * HID + j] * nrm);
}

__global__ void k_mlp2(const float* __restrict__ agg1, const float* __restrict__ b1,
                       const float* __restrict__ W2, const float* __restrict__ dinv,
                       float* __restrict__ h2p, float* __restrict__ agg2p) {
    int i = blockIdx.x * blockDim.x + threadIdx.x;
    if (i >= NN) return;
    const float4* a4 = reinterpret_cast<const float4*>(agg1 + (size_t)i * HID);
    float4 t0 = a4[0], t1 = a4[1], t2 = a4[2], t3 = a4[3];
    float v[16] = {t0.x, t0.y, t0.z, t0.w, t1.x, t1.y, t1.z, t1.w,
                   t2.x, t2.y, t2.z, t2.w, t3.x, t3.y, t3.z, t3.w};
#pragma unroll
    for (int k = 0; k < 16; ++k) v[k] = fmaxf(v[k] + b1[k], 0.f);
    float o[8] = {0.f, 0.f, 0.f, 0.f, 0.f, 0.f, 0.f, 0.f};
#pragma unroll
    for (int k = 0; k < 16; ++k)
#pragma unroll
        for (int j = 0; j < 7; ++j) o[j] = fmaf(v[k], W2[k * 7 + j], o[j]);
    float4* hp = reinterpret_cast<float4*>(h2p + (size_t)i * H2P);
    hp[0] = make_float4(o[0], o[1], o[2], o[3]);
    hp[1] = make_float4(o[4], o[5], o[6], 0.f);
    if (agg2p) {
        float di = dinv[i];
        float d2 = di * di;
        float4* ap = reinterpret_cast<float4*>(agg2p + (size_t)i * H2P);
        ap[0] = make_float4(o[0] * d2, o[1] * d2, o[2] * d2, o[3] * d2);
        ap[1] = make_float4(o[4] * d2, o[5] * d2, o[6] * d2, 0.f);
    }
}

__global__ void k_scatter2f(const int* __restrict__ ei, const float* __restrict__ dinv,
                            const float* __restrict__ h2p, float* __restrict__ agg2p) {
    int t = blockIdx.x * blockDim.x + threadIdx.x;
    int e = t >> 3, j = t & 7;
    if (e >= EE || j >= OUTD) return;
    int r = ei[e], c = ei[EE + e];
    float nrm = dinv[r] * dinv[c];
    atomicAdd(&agg2p[(size_t)r * H2P + j], h2p[(size_t)c * H2P + j] * nrm);
}

__global__ void k_logsoftmax(const float* __restrict__ agg2p, const float* __restrict__ b2,
                             float* __restrict__ out) {
    int i = blockIdx.x * blockDim.x + threadIdx.x;
    if (i >= NN) return;
    const float4* ap = reinterpret_cast<const float4*>(agg2p + (size_t)i * H2P);
    float4 a = ap[0], b = ap[1];
    float v[7] = {a.x, a.y, a.z, a.w, b.x, b.y, b.z};
#pragma unroll
    for (int j = 0; j < 7; ++j) v[j] += b2[j];
    float m = v[0];
#pragma unroll
    for (int j = 1; j < 7; ++j) m = fmaxf(m, v[j]);
    float ssum = 0.f;
#pragma unroll
    for (int j = 0; j < 7; ++j) ssum += expf(v[j] - m);
    float ls = logf(ssum);
#pragma unroll
    for (int j = 0; j < 7; ++j) out[(size_t)i * OUTD + j] = v[j] - m - ls;
}

// ============================ launch ============================

extern "C" void kernel_launch(void* const* d_in, const int* in_sizes, int n_in,
                              void* d_out, int out_size, void* d_ws, size_t ws_size,
                              hipStream_t stream) {
    const float* x  = (const float*)d_in[0];
    const int*   ei = (const int*)d_in[1];     // [2, E] flattened
    const float* W1 = (const float*)d_in[2];
    const float* b1 = (const float*)d_in[3];
    const float* W2 = (const float*)d_in[4];
    const float* b2 = (const float*)d_in[5];
    float* out = (float*)d_out;
    float* ws  = (float*)d_ws;

    float* dinv = ws;                       // N
    float* h1   = ws + NN;                  // 16N
    float* h2p  = ws + NN + 16 * NN;        // 8N  (CSR path; also fallback agg1 overlays here)

    const size_t need_csr = (size_t)(33 * NN) * 4 + (size_t)(3 * NN + 1 + EE + 64) * 4;
    const bool csr = ws_size >= need_csr;

    if (csr) {
        int* ibase  = (int*)(ws + (size_t)33 * NN);
        int* cnt    = ibase;                 // N
        int* rowptr = ibase + NN;            // N+1
        int* cursor = ibase + 2 * NN + 1;    // N
        int* scol   = ibase + 3 * NN + 1;    // E
        int* bsum   = scol + EE;             // 32
        int* boffs  = bsum + 32;             // 32

        hipLaunchKernelGGL(k_zero_i32, dim3((NN + 255) / 256), dim3(256), 0, stream, cnt, NN);
        hipLaunchKernelGGL(k_count, dim3((EE + 255) / 256), dim3(256), 0, stream, ei, cnt);
        hipLaunchKernelGGL(k_dinv_from_cnt, dim3((NN + 255) / 256), dim3(256), 0, stream,
                           cnt, dinv);
        hipLaunchKernelGGL(k_scan1, dim3(NB_SCAN), dim3(SCAN_TPB), 0, stream,
                           cnt, rowptr, bsum);
        hipLaunchKernelGGL(k_scan2, dim3(1), dim3(64), 0, stream, bsum, boffs, rowptr);
        hipLaunchKernelGGL(k_scan3, dim3(NB_SCAN), dim3(SCAN_TPB), 0, stream,
                           boffs, rowptr, cursor);
        hipLaunchKernelGGL(k_place, dim3((EE + 255) / 256), dim3(256), 0, stream,
                           ei, cursor, scol);
        hipLaunchKernelGGL(k_gemm1, dim3((NN + RB - 1) / RB), dim3(256), 0, stream,
                           x, W1, h1);
        hipLaunchKernelGGL(k_agg1m, dim3(NN / 4), dim3(256), 0, stream,
                           rowptr, scol, dinv, h1, b1, W2, h2p);
        hipLaunchKernelGGL(k_agg2, dim3(NN / 4), dim3(256), 0, stream,
                           rowptr, scol, dinv, h2p, b2, out);
    } else {
        // atomic fallback (R1-proven): needs 33N floats + N ints
        float* agg1  = ws + NN + 16 * NN;    // 16N
        float* h2pf  = h1;                   // 8N over dead h1
        float* agg2p = h1 + 8 * NN;          // 8N
        int* cnt = (int*)agg1;               // dead until after k_dinv_from_cnt
        hipLaunchKernelGGL(k_zero_i32, dim3((NN + 255) / 256), dim3(256), 0, stream, cnt, NN);
        hipLaunchKernelGGL(k_count, dim3((EE + 255) / 256), dim3(256), 0, stream, ei, cnt);
        hipLaunchKernelGGL(k_dinv_from_cnt, dim3((NN + 255) / 256), dim3(256), 0, stream,
                           cnt, dinv);
        hipLaunchKernelGGL(k_gemm1, dim3((NN + RB - 1) / RB), dim3(256), 0, stream,
                           x, W1, h1);
        hipLaunchKernelGGL(k_selfloop1, dim3((NN * HID + 255) / 256), dim3(256), 0, stream,
                           h1, dinv, agg1);
        hipLaunchKernelGGL(k_scatter1f, dim3((EE * HID) / 256), dim3(256), 0, stream,
                           ei, dinv, h1, agg1);
        hipLaunchKernelGGL(k_mlp2, dim3((NN + 255) / 256), dim3(256), 0, stream,
                           agg1, b1, W2, dinv, h2pf, agg2p);
        hipLaunchKernelGGL(k_scatter2f, dim3((EE * 8) / 256), dim3(256), 0, stream,
                           ei, dinv, h2pf, agg2p);
        hipLaunchKernelGGL(k_logsoftmax, dim3((NN + 255) / 256), dim3(256), 0, stream,
                           agg2p, b2, out);
    }
}

// Round 6
// 570.326 us; speedup vs baseline: 7.6230x; 1.0253x over previous
//
#include <hip/hip_runtime.h>
#include <hip/hip_bf16.h>

#define NN   100000
#define EE   3200000
#define KDIM 1433
#define HID  16
#define H2P  8
#define OUTD 7

// ---- gemm1 tiling ----
#define KC    128
#define RB    64
#define XSTR  133            // lane stride 133 mod 32 = 5 (odd) -> 2-way LDS aliasing = free
#define NCHUNK ((KDIM + KC - 1) / KC)   // 12
#define NTIL  ((NN + RB - 1) / RB)      // 1563
#define GBLK  1024                       // persistent blocks (4/CU)

// ---- scan tiling ----
#define SCAN_TPB   1024
#define SCAN_ELEMS 4096
#define NB_SCAN    ((NN + SCAN_ELEMS - 1) / SCAN_ELEMS)   // 25

__device__ inline unsigned short f2bf(float f) {        // fp32 -> bf16 rn
    unsigned u = __float_as_uint(f);
    unsigned r = (u + 0x7FFFu + ((u >> 16) & 1u)) >> 16;
    return (unsigned short)r;
}

// ============================ degree / norm / CSR ============================

__global__ void k_zero_i32(int* __restrict__ p, int n) {
    int i = blockIdx.x * blockDim.x + threadIdx.x;
    if (i < n) p[i] = 0;
}

__global__ void k_count(const int* __restrict__ ei, int* __restrict__ cnt) {
    int e = blockIdx.x * blockDim.x + threadIdx.x;
    if (e < EE) atomicAdd(&cnt[ei[e]], 1);      // row = ei[0][e]
}

__global__ void k_dinv_from_cnt(const int* __restrict__ cnt, float* __restrict__ dinv) {
    int i = blockIdx.x * blockDim.x + threadIdx.x;
    if (i < NN) dinv[i] = rsqrtf((float)cnt[i] + 1.0f);   // +1 self-loop
}

// per-block scan; also emits dinv (fused k_dinv_from_cnt)
__global__ __launch_bounds__(SCAN_TPB) void k_scan1(const int* __restrict__ cnt,
                                                    int* __restrict__ rowptr,
                                                    int* __restrict__ bsum,
                                                    float* __restrict__ dinv) {
    __shared__ int spart[16];
    const int tid = threadIdx.x;
    const int L = tid & 63;
    const int w = tid >> 6;
    const int i0 = blockIdx.x * SCAN_ELEMS + tid * 4;
    int v0 = (i0 + 0 < NN) ? cnt[i0 + 0] : 0;
    int v1 = (i0 + 1 < NN) ? cnt[i0 + 1] : 0;
    int v2 = (i0 + 2 < NN) ? cnt[i0 + 2] : 0;
    int v3 = (i0 + 3 < NN) ? cnt[i0 + 3] : 0;
    if (i0 + 0 < NN) dinv[i0 + 0] = rsqrtf((float)v0 + 1.0f);
    if (i0 + 1 < NN) dinv[i0 + 1] = rsqrtf((float)v1 + 1.0f);
    if (i0 + 2 < NN) dinv[i0 + 2] = rsqrtf((float)v2 + 1.0f);
    if (i0 + 3 < NN) dinv[i0 + 3] = rsqrtf((float)v3 + 1.0f);
    int local = v0 + v1 + v2 + v3;
    int s = local;
#pragma unroll
    for (int ofs = 1; ofs < 64; ofs <<= 1) {
        int n = __shfl_up(s, ofs, 64);
        if (L >= ofs) s += n;
    }
    if (L == 63) spart[w] = s;
    __syncthreads();
    if (w == 0) {
        int p = (L < 16) ? spart[L] : 0;
#pragma unroll
        for (int ofs = 1; ofs < 16; ofs <<= 1) {
            int n = __shfl_up(p, ofs, 64);
            if (L >= ofs) p += n;
        }
        if (L < 16) spart[L] = p;
    }
    __syncthreads();
    int waveoff = (w > 0) ? spart[w - 1] : 0;
    int excl = waveoff + s - local;                 // block-local exclusive
    if (i0 + 0 < NN) { rowptr[i0 + 0] = excl; excl += v0; }
    if (i0 + 1 < NN) { rowptr[i0 + 1] = excl; excl += v1; }
    if (i0 + 2 < NN) { rowptr[i0 + 2] = excl; excl += v2; }
    if (i0 + 3 < NN) { rowptr[i0 + 3] = excl; excl += v3; }
    if (tid == 0) bsum[blockIdx.x] = spart[15];
}

__global__ void k_scan2(const int* __restrict__ bsum, int* __restrict__ boffs,
                        int* __restrict__ rowptr) {
    int L = threadIdx.x;   // one wave
    int v = (L < NB_SCAN) ? bsum[L] : 0;
    int s = v;
#pragma unroll
    for (int ofs = 1; ofs < 64; ofs <<= 1) {
        int n = __shfl_up(s, ofs, 64);
        if (L >= ofs) s += n;
    }
    if (L < NB_SCAN) boffs[L] = s - v;
    if (L == NB_SCAN - 1) rowptr[NN] = s;          // grand total (=EE)
}

__global__ __launch_bounds__(SCAN_TPB) void k_scan3(const int* __restrict__ boffs,
                                                    int* __restrict__ rowptr,
                                                    int* __restrict__ cursor) {
    const int off = boffs[blockIdx.x];
    const int i0 = blockIdx.x * SCAN_ELEMS + threadIdx.x * 4;
#pragma unroll
    for (int t = 0; t < 4; ++t) {
        int i = i0 + t;
        if (i < NN) {
            int v = rowptr[i] + off;
            rowptr[i] = v;
            cursor[i] = v;
        }
    }
}

__global__ void k_place(const int* __restrict__ ei, int* __restrict__ cursor,
                        int* __restrict__ scol) {
    int e = blockIdx.x * blockDim.x + threadIdx.x;
    if (e >= EE) return;
    int r = ei[e], c = ei[EE + e];
    int p = atomicAdd(&cursor[r], 1);
    scol[p] = c;
}

// ============================ layer 1 GEMM ============================

// Persistent grid (1024 blocks), software pipeline continues ACROSS tiles:
// the chunk-(c+1) prefetch of tile t's last chunk loads tile t+GBLK chunk 0,
// so the load pipeline never drains between tiles.
// Output: if h1b != null, writes bf16 h1s[i] = (x@W1)[i] * dscale[i] (32B/row);
// else writes raw fp32 h1 (fallback path).
__global__ __launch_bounds__(256) void k_gemm1(const float* __restrict__ x,
                                               const float* __restrict__ W1,
                                               const float* __restrict__ dscale,
                                               unsigned short* __restrict__ h1b,
                                               float* __restrict__ h1f) {
    __shared__ __align__(16) float xs[RB * XSTR];   // 34 KB -> 4 blocks/CU
    const int tid = threadIdx.x;
    const int wu  = __builtin_amdgcn_readfirstlane(tid >> 6);  // W1 loads -> s_load
    const int L   = tid & 63;
    const int kk    = tid & 127;
    const int rbase = tid >> 7;              // 0 or 1

    float tmp[32];

    auto stage = [&](int t, int c) {
        const int r0t = t * RB;
        const int c0t = c * KC;
        const int kv  = (KDIM - c0t < KC) ? (KDIM - c0t) : KC;
        const float* xp = x + (size_t)(r0t + rbase) * KDIM + c0t + kk;
        if ((r0t + RB) <= NN && kv == KC) {
#pragma unroll
            for (int m = 0; m < 32; ++m) tmp[m] = xp[(size_t)(2 * m) * KDIM];
        } else {
            const bool kok = kk < kv;
#pragma unroll
            for (int m = 0; m < 32; ++m) {
                int gr = r0t + rbase + 2 * m;
                tmp[m] = (kok && gr < NN) ? xp[(size_t)(2 * m) * KDIM] : 0.f;
            }
        }
    };

    stage((int)blockIdx.x, 0);               // prologue

    for (int tile = blockIdx.x; tile < NTIL; tile += GBLK) {
        const int r0 = tile * RB;
        float acc[HID];
#pragma unroll
        for (int j = 0; j < HID; ++j) acc[j] = 0.f;

        for (int c = 0; c < NCHUNK; ++c) {
            const int c0 = c * KC;
            const int kvalid = (KDIM - c0 < KC) ? (KDIM - c0) : KC;
            __syncthreads();                 // xs free (prev compute / red4 reads done)
#pragma unroll
            for (int m = 0; m < 32; ++m) {   // vmcnt drain happens here
                xs[(rbase + 2 * m) * XSTR + kk] = tmp[m];
            }
            __syncthreads();

            // prefetch next chunk (possibly next tile's chunk 0)
            int nt = tile, nc = c + 1;
            if (nc == NCHUNK) { nt += GBLK; nc = 0; }
            if (nt < NTIL) stage(nt, nc);

            // compute: wave wu covers kk in [wu*32, wu*32+32)
            int kend = kvalid - wu * 32;
            kend = kend < 0 ? 0 : (kend > 32 ? 32 : kend);
            const float* wbase = W1 + (size_t)(c0 + wu * 32) * HID;
            const float* xbase = xs + L * XSTR + wu * 32;
#pragma unroll 4
            for (int i = 0; i < kend; ++i) {
                float xv = xbase[i];
                const float* wr = wbase + i * HID;
#pragma unroll
                for (int j = 0; j < HID; ++j) acc[j] = fmaf(xv, wr[j], acc[j]);
            }
        }

        // ---- epilogue: cross-wave k-reduction via LDS ----
        __syncthreads();
        float4* red4 = reinterpret_cast<float4*>(xs);
        red4[(wu * 64 + L) * 4 + 0] = make_float4(acc[0], acc[1], acc[2], acc[3]);
        red4[(wu * 64 + L) * 4 + 1] = make_float4(acc[4], acc[5], acc[6], acc[7]);
        red4[(wu * 64 + L) * 4 + 2] = make_float4(acc[8], acc[9], acc[10], acc[11]);
        red4[(wu * 64 + L) * 4 + 3] = make_float4(acc[12], acc[13], acc[14], acc[15]);
        __syncthreads();
        int rr = tid >> 2, jj = tid & 3;
        float4 a = red4[(0 * 64 + rr) * 4 + jj];
        float4 b = red4[(1 * 64 + rr) * 4 + jj];
        float4 cf = red4[(2 * 64 + rr) * 4 + jj];
        float4 d = red4[(3 * 64 + rr) * 4 + jj];
        float4 s = make_float4(a.x + b.x + cf.x + d.x, a.y + b.y + cf.y + d.y,
                               a.z + b.z + cf.z + d.z, a.w + b.w + cf.w + d.w);
        int gr = r0 + rr;
        if (gr < NN) {
            if (h1b) {
                float sc = dscale[gr];
                unsigned u0 = (unsigned)f2bf(s.x * sc) | ((unsigned)f2bf(s.y * sc) << 16);
                unsigned u1 = (unsigned)f2bf(s.z * sc) | ((unsigned)f2bf(s.w * sc) << 16);
                reinterpret_cast<uint2*>(h1b)[(size_t)gr * 4 + jj] = make_uint2(u0, u1);
            } else {
                reinterpret_cast<float4*>(h1f)[(size_t)gr * 4 + jj] = s;
            }
        }
        // next loop iteration's first __syncthreads protects xs reuse
    }
}

// ============================ fused CSR aggregation + layer-2 matvec ============================

// agg1[r] = dinv[r] * (sum_{c in N(r)} h1s[c] + h1s[r]);  v=relu(agg1+b1);
// o = v @ W2;  h2s[r] = o * dinv[r].
// 4 rows/block (1 wave each); lane = 16 edge-slots x 4 quarters (4 bf16 = 8B each).
__global__ __launch_bounds__(256) void k_agg1m(const int* __restrict__ rowptr,
                                               const int* __restrict__ scol,
                                               const float* __restrict__ dinv,
                                               const unsigned short* __restrict__ h1b,
                                               const float* __restrict__ b1,
                                               const float* __restrict__ W2,
                                               float* __restrict__ h2s) {
    int row = blockIdx.x * 4 + (threadIdx.x >> 6);
    int L = threadIdx.x & 63;
    int ee = L >> 2;        // 0..15 edge slot
    int q  = L & 3;         // quarter of the 16-feature row
    int s = rowptr[row], eend = rowptr[row + 1];
    float dr = dinv[row];
    const uint2* h1q = reinterpret_cast<const uint2*>(h1b);
    float4 acc = make_float4(0.f, 0.f, 0.f, 0.f);
    for (int k = s + ee; k < eend; k += 16) {
        int c = scol[k];
        uint2 hv = h1q[(size_t)c * 4 + q];
        acc.x += __uint_as_float(hv.x << 16);
        acc.y += __uint_as_float(hv.x & 0xFFFF0000u);
        acc.z += __uint_as_float(hv.y << 16);
        acc.w += __uint_as_float(hv.y & 0xFFFF0000u);
    }
#pragma unroll
    for (int mask = 4; mask <= 32; mask <<= 1) {
        acc.x += __shfl_xor(acc.x, mask, 64);
        acc.y += __shfl_xor(acc.y, mask, 64);
        acc.z += __shfl_xor(acc.z, mask, 64);
        acc.w += __shfl_xor(acc.w, mask, 64);
    }
    uint2 sv = h1q[(size_t)row * 4 + q];          // self term (already *dinv[row])
    acc.x = (acc.x + __uint_as_float(sv.x << 16)) * dr;
    acc.y = (acc.y + __uint_as_float(sv.x & 0xFFFF0000u)) * dr;
    acc.z = (acc.z + __uint_as_float(sv.y << 16)) * dr;
    acc.w = (acc.w + __uint_as_float(sv.y & 0xFFFF0000u)) * dr;
    // assemble the full 16-vector in every lane (quarter qq lives in lane (L&~3)|qq)
    float v[16];
#pragma unroll
    for (int qq = 0; qq < 4; ++qq) {
        int src = (L & ~3) | qq;
        v[qq * 4 + 0] = __shfl(acc.x, src, 64);
        v[qq * 4 + 1] = __shfl(acc.y, src, 64);
        v[qq * 4 + 2] = __shfl(acc.z, src, 64);
        v[qq * 4 + 3] = __shfl(acc.w, src, 64);
    }
#pragma unroll
    for (int k = 0; k < 16; ++k) v[k] = fmaxf(v[k] + b1[k], 0.f);
    if (L < 8) {
        int j = (L < 7) ? L : 0;
        float o = 0.f;
#pragma unroll
        for (int k = 0; k < 16; ++k) o = fmaf(v[k], W2[k * 7 + j], o);
        h2s[(size_t)row * H2P + L] = (L < 7) ? o * dr : 0.f;
    }
}

// out[r] = logsoftmax(dinv[r]*(sum h2s[c] + h2s[r]) + b2)
// 4 rows/block; lane = 8 edge-slots x 8 features.
__global__ __launch_bounds__(256) void k_agg2(const int* __restrict__ rowptr,
                                              const int* __restrict__ scol,
                                              const float* __restrict__ dinv,
                                              const float* __restrict__ h2s,
                                              const float* __restrict__ b2,
                                              float* __restrict__ out) {
    int row = blockIdx.x * 4 + (threadIdx.x >> 6);
    int L = threadIdx.x & 63;
    int ee = L >> 3, j = L & 7;
    int s = rowptr[row], eend = rowptr[row + 1];
    float dr = dinv[row];
    float acc = 0.f;
    for (int k = s + ee; k < eend; k += 8) {
        int c = scol[k];
        acc += h2s[(size_t)c * H2P + j];
    }
    acc += __shfl_xor(acc, 8, 64);
    acc += __shfl_xor(acc, 16, 64);
    acc += __shfl_xor(acc, 32, 64);
    acc += h2s[(size_t)row * H2P + j];
    float v = acc * dr + ((j < 7) ? b2[j] : 0.f);
    if (j == 7) v = -3.0e38f;
    float m = v;
    m = fmaxf(m, __shfl_xor(m, 1, 64));
    m = fmaxf(m, __shfl_xor(m, 2, 64));
    m = fmaxf(m, __shfl_xor(m, 4, 64));
    float ex = (j < 7) ? expf(v - m) : 0.f;
    float ssum = ex;
    ssum += __shfl_xor(ssum, 1, 64);
    ssum += __shfl_xor(ssum, 2, 64);
    ssum += __shfl_xor(ssum, 4, 64);
    float ls = logf(ssum);
    if (j < 7) out[(size_t)row * OUTD + j] = v - m - ls;
}

// ============================ fallback (small ws): atomic path ============================

__global__ void k_selfloop1(const float* __restrict__ h1, const float* __restrict__ dinv,
                            float* __restrict__ agg1) {
    int t = blockIdx.x * blockDim.x + threadIdx.x;
    if (t >= NN * HID) return;
    int i = t >> 4;
    float di = dinv[i];
    agg1[t] = h1[t] * di * di;
}

__global__ void k_scatter1f(const int* __restrict__ ei, const float* __restrict__ dinv,
                            const float* __restrict__ h1, float* __restrict__ agg1) {
    int t = blockIdx.x * blockDim.x + threadIdx.x;
    int e = t >> 4, j = t & 15;
    if (e >= EE) return;
    int r = ei[e], c = ei[EE + e];
    float nrm = dinv[r] * dinv[c];
    atomicAdd(&agg1[(size_t)r * HID + j], h1[(size_t)c * HID + j] * nrm);
}

__global__ void k_mlp2(const float* __restrict__ agg1, const float* __restrict__ b1,
                       const float* __restrict__ W2, const float* __restrict__ dinv,
                       float* __restrict__ h2p, float* __restrict__ agg2p) {
    int i = blockIdx.x * blockDim.x + threadIdx.x;
    if (i >= NN) return;
    const float4* a4 = reinterpret_cast<const float4*>(agg1 + (size_t)i * HID);
    float4 t0 = a4[0], t1 = a4[1], t2 = a4[2], t3 = a4[3];
    float v[16] = {t0.x, t0.y, t0.z, t0.w, t1.x, t1.y, t1.z, t1.w,
                   t2.x, t2.y, t2.z, t2.w, t3.x, t3.y, t3.z, t3.w};
#pragma unroll
    for (int k = 0; k < 16; ++k) v[k] = fmaxf(v[k] + b1[k], 0.f);
    float o[8] = {0.f, 0.f, 0.f, 0.f, 0.f, 0.f, 0.f, 0.f};
#pragma unroll
    for (int k = 0; k < 16; ++k)
#pragma unroll
        for (int j = 0; j < 7; ++j) o[j] = fmaf(v[k], W2[k * 7 + j], o[j]);
    float4* hp = reinterpret_cast<float4*>(h2p + (size_t)i * H2P);
    hp[0] = make_float4(o[0], o[1], o[2], o[3]);
    hp[1] = make_float4(o[4], o[5], o[6], 0.f);
    if (agg2p) {
        float di = dinv[i];
        float d2 = di * di;
        float4* ap = reinterpret_cast<float4*>(agg2p + (size_t)i * H2P);
        ap[0] = make_float4(o[0] * d2, o[1] * d2, o[2] * d2, o[3] * d2);
        ap[1] = make_float4(o[4] * d2, o[5] * d2, o[6] * d2, 0.f);
    }
}

__global__ void k_scatter2f(const int* __restrict__ ei, const float* __restrict__ dinv,
                            const float* __restrict__ h2p, float* __restrict__ agg2p) {
    int t = blockIdx.x * blockDim.x + threadIdx.x;
    int e = t >> 3, j = t & 7;
    if (e >= EE || j >= OUTD) return;
    int r = ei[e], c = ei[EE + e];
    float nrm = dinv[r] * dinv[c];
    atomicAdd(&agg2p[(size_t)r * H2P + j], h2p[(size_t)c * H2P + j] * nrm);
}

__global__ void k_logsoftmax(const float* __restrict__ agg2p, const float* __restrict__ b2,
                             float* __restrict__ out) {
    int i = blockIdx.x * blockDim.x + threadIdx.x;
    if (i >= NN) return;
    const float4* ap = reinterpret_cast<const float4*>(agg2p + (size_t)i * H2P);
    float4 a = ap[0], b = ap[1];
    float v[7] = {a.x, a.y, a.z, a.w, b.x, b.y, b.z};
#pragma unroll
    for (int j = 0; j < 7; ++j) v[j] += b2[j];
    float m = v[0];
#pragma unroll
    for (int j = 1; j < 7; ++j) m = fmaxf(m, v[j]);
    float ssum = 0.f;
#pragma unroll
    for (int j = 0; j < 7; ++j) ssum += expf(v[j] - m);
    float ls = logf(ssum);
#pragma unroll
    for (int j = 0; j < 7; ++j) out[(size_t)i * OUTD + j] = v[j] - m - ls;
}

// ============================ launch ============================

extern "C" void kernel_launch(void* const* d_in, const int* in_sizes, int n_in,
                              void* d_out, int out_size, void* d_ws, size_t ws_size,
                              hipStream_t stream) {
    const float* x  = (const float*)d_in[0];
    const int*   ei = (const int*)d_in[1];     // [2, E] flattened
    const float* W1 = (const float*)d_in[2];
    const float* b1 = (const float*)d_in[3];
    const float* W2 = (const float*)d_in[4];
    const float* b2 = (const float*)d_in[5];
    float* out = (float*)d_out;
    float* ws  = (float*)d_ws;

    float* dinv = ws;                        // N floats
    unsigned short* h1b = (unsigned short*)(ws + NN);   // 16N bf16 = 8N float slots
    float* h2s  = ws + NN + 16 * NN;         // 8N floats (CSR path)

    const size_t need_csr = (size_t)(33 * NN) * 4 + (size_t)(3 * NN + 1 + EE + 64) * 4;
    const bool csr = ws_size >= need_csr;

    if (csr) {
        int* ibase  = (int*)(ws + (size_t)33 * NN);
        int* cnt    = ibase;                 // N
        int* rowptr = ibase + NN;            // N+1
        int* cursor = ibase + 2 * NN + 1;    // N
        int* scol   = ibase + 3 * NN + 1;    // E
        int* bsum   = scol + EE;             // 32
        int* boffs  = bsum + 32;             // 32

        hipLaunchKernelGGL(k_zero_i32, dim3((NN + 255) / 256), dim3(256), 0, stream, cnt, NN);
        hipLaunchKernelGGL(k_count, dim3((EE + 255) / 256), dim3(256), 0, stream, ei, cnt);
        hipLaunchKernelGGL(k_scan1, dim3(NB_SCAN), dim3(SCAN_TPB), 0, stream,
                           cnt, rowptr, bsum, dinv);
        hipLaunchKernelGGL(k_scan2, dim3(1), dim3(64), 0, stream, bsum, boffs, rowptr);
        hipLaunchKernelGGL(k_scan3, dim3(NB_SCAN), dim3(SCAN_TPB), 0, stream,
                           boffs, rowptr, cursor);
        hipLaunchKernelGGL(k_place, dim3((EE + 255) / 256), dim3(256), 0, stream,
                           ei, cursor, scol);
        hipLaunchKernelGGL(k_gemm1, dim3(GBLK), dim3(256), 0, stream,
                           x, W1, dinv, h1b, (float*)nullptr);
        hipLaunchKernelGGL(k_agg1m, dim3(NN / 4), dim3(256), 0, stream,
                           rowptr, scol, dinv, h1b, b1, W2, h2s);
        hipLaunchKernelGGL(k_agg2, dim3(NN / 4), dim3(256), 0, stream,
                           rowptr, scol, dinv, h2s, b2, out);
    } else {
        // atomic fallback (R1-proven): needs 33N floats + N ints
        float* h1    = ws + NN;              // 16N fp32
        float* agg1  = ws + NN + 16 * NN;    // 16N
        float* h2pf  = h1;                   // 8N over dead h1
        float* agg2p = h1 + 8 * NN;          // 8N
        int* cnt = (int*)agg1;               // dead until after k_dinv_from_cnt
        hipLaunchKernelGGL(k_zero_i32, dim3((NN + 255) / 256), dim3(256), 0, stream, cnt, NN);
        hipLaunchKernelGGL(k_count, dim3((EE + 255) / 256), dim3(256), 0, stream, ei, cnt);
        hipLaunchKernelGGL(k_dinv_from_cnt, dim3((NN + 255) / 256), dim3(256), 0, stream,
                           cnt, dinv);
        hipLaunchKernelGGL(k_gemm1, dim3(GBLK), dim3(256), 0, stream,
                           x, W1, (const float*)nullptr, (unsigned short*)nullptr, h1);
        hipLaunchKernelGGL(k_selfloop1, dim3((NN * HID + 255) / 256), dim3(256), 0, stream,
                           h1, dinv, agg1);
        hipLaunchKernelGGL(k_scatter1f, dim3((EE * HID) / 256), dim3(256), 0, stream,
                           ei, dinv, h1, agg1);
        hipLaunchKernelGGL(k_mlp2, dim3((NN + 255) / 256), dim3(256), 0, stream,
                           agg1, b1, W2, dinv, h2pf, agg2p);
        hipLaunchKernelGGL(k_scatter2f, dim3((EE * 8) / 256), dim3(256), 0, stream,
                           ei, dinv, h2pf, agg2p);
        hipLaunchKernelGGL(k_logsoftmax, dim3((NN + 255) / 256), dim3(256), 0, stream,
                           agg2p, b2, out);
    }
}